// Round 16
// baseline (710.439 us; speedup 1.0000x reference)
//
#include <hip/hip_runtime.h>
#include <math.h>

typedef __attribute__((ext_vector_type(8))) short short8;
typedef __attribute__((ext_vector_type(4))) float f32x4;

// ---------------------------------------------------------------- utilities
__device__ __forceinline__ float wave_sum(float v){
  #pragma unroll
  for (int m = 32; m; m >>= 1) v += __shfl_xor(v, m, 64);
  return v;
}
__device__ __forceinline__ unsigned fenc(float f){
  unsigned u = __float_as_uint(f);
  return (u >> 31) ? ~u : (u | 0x80000000u);
}
__device__ __forceinline__ float fdec(unsigned e){
  return (e >> 31) ? __uint_as_float(e & 0x7fffffffu) : __uint_as_float(~e);
}
__device__ __forceinline__ float sigm(float x){ return 1.f / (1.f + __expf(-x)); }
__device__ __forceinline__ unsigned short f2bf(float f){
  union { float f; unsigned u; } x; x.f = f;
  unsigned r = x.u + 0x7fffu + ((x.u >> 16) & 1u);
  return (unsigned short)(r >> 16);
}
__device__ __forceinline__ float bf2f(unsigned short h){
  union { unsigned u; float f; } x; x.u = ((unsigned)h) << 16;
  return x.f;
}

// ------------------------------------------------------------ CSR building
__global__ void k_build_edges(const int* __restrict__ ei, int E2, int E,
                              int* __restrict__ src, int* __restrict__ dst,
                              int* __restrict__ deg){
  int e = blockIdx.x * blockDim.x + threadIdx.x;
  if (e >= E2) return;
  int s = ei[e];
  int d = (e < E) ? ei[e + E] : ei[e - E];
  src[e] = s; dst[e] = d;
  atomicAdd(&deg[d], 1);
}

__global__ void k_scan(const int* __restrict__ deg, int* __restrict__ rowptr, int N){
  __shared__ int part[1024];
  int t = threadIdx.x;
  int chunk = (N + 1023) / 1024;
  int lo = t * chunk, hi = lo + chunk; if (hi > N) hi = N;
  int s = 0;
  for (int i = lo; i < hi; ++i) s += deg[i];
  part[t] = s;
  __syncthreads();
  for (int off = 1; off < 1024; off <<= 1){
    int v = (t >= off) ? part[t - off] : 0;
    __syncthreads();
    part[t] += v;
    __syncthreads();
  }
  int run = part[t] - s;
  for (int i = lo; i < hi; ++i){ rowptr[i] = run; run += deg[i]; }
  if (t == 1023) rowptr[N] = part[1023];
}

// fill CSR + gather raw edge features once (edge-per-lane, lane-parallel)
__global__ void k_fill(const int* __restrict__ src, const int* __restrict__ dst,
                       const int* __restrict__ rowptr,
                       int* __restrict__ cur, int* __restrict__ csrc,
                       int* __restrict__ epos,
                       const float* __restrict__ x, const float* __restrict__ ea,
                       float* __restrict__ re8, int E2, int E){
  int e = blockIdx.x * blockDim.x + threadIdx.x;
  if (e >= E2) return;
  int s = src[e], d = dst[e];
  int pos = rowptr[d] + atomicAdd(&cur[d], 1);
  csrc[pos] = s;
  epos[e] = pos;
  int row = (e < E) ? e : e - E;
  float4 eav = *reinterpret_cast<const float4*>(ea + (size_t)row*4);
  float r0 = x[s*6]     - x[d*6];
  float r1 = x[s*6 + 1] - x[d*6 + 1];
  float r2 = x[s*6 + 2] - x[d*6 + 2];
  *reinterpret_cast<float4*>(re8 + (size_t)e*8)     = eav;
  *reinterpret_cast<float4*>(re8 + (size_t)e*8 + 4) = make_float4(r0, r1, r2, 0.f);
}

// ------------------------- fused node embedding + column pool (max/mean)
__global__ void k_embed_pool(const float* __restrict__ x, const float* __restrict__ nw,
                             const float* __restrict__ nb, const float* __restrict__ zemb,
                             float* __restrict__ nf,
                             unsigned* __restrict__ pmax, float* __restrict__ psum, int N){
  int tx = threadIdx.x & 63;
  int ty = threadIdx.x >> 6;
  const float allowed[6] = {8.f, 23.f, 39.f, 54.f, 90.f, 180.f};
  float m = -INFINITY, s = 0.f;
  for (int n = blockIdx.x*4 + ty; n < N; n += gridDim.x*4){
    float xv[6];
    #pragma unroll
    for (int k = 0; k < 6; ++k) xv[k] = x[n*6 + k];
    float v = nb[tx];
    #pragma unroll
    for (int k = 0; k < 6; ++k) v += xv[k] * nw[k*64 + tx];
    v = fmaxf(v, 0.f);
    float r = rintf(xv[2]);
    int zi = 0; float bd = fabsf(r - allowed[0]);
    #pragma unroll
    for (int k = 1; k < 6; ++k){ float d = fabsf(r - allowed[k]); if (d < bd){ bd = d; zi = k; } }
    v += zemb[zi*64 + tx];
    nf[(size_t)n*64 + tx] = v;
    m = fmaxf(m, v); s += v;
  }
  __shared__ float sm[4][64], ss[4][64];
  sm[ty][tx] = m; ss[ty][tx] = s;
  __syncthreads();
  if (ty == 0){
    #pragma unroll
    for (int k = 1; k < 4; ++k){ m = fmaxf(m, sm[k][tx]); s += ss[k][tx]; }
    atomicMax(&pmax[tx], fenc(m));
    atomicAdd(&psum[tx], s);
  }
}

// ------------------------------------------------------------------- CBAM MLP
__global__ void k_cbam_mlp(const unsigned* __restrict__ pmax, const float* __restrict__ psum,
                           float invR,
                           const float* __restrict__ w1, const float* __restrict__ b1,
                           const float* __restrict__ w2, const float* __restrict__ b2,
                           float* __restrict__ ch){
  __shared__ float pool[128];
  __shared__ float h[4];
  int t = threadIdx.x;
  pool[t]      = fdec(pmax[t]);
  pool[64 + t] = psum[t] * invR;
  __syncthreads();
  if (t < 4){
    float a = b1[t];
    for (int k = 0; k < 128; ++k) a += pool[k] * w1[k*4 + t];
    h[t] = fmaxf(a, 0.f);
  }
  __syncthreads();
  float a = b2[t];
  #pragma unroll
  for (int k = 0; k < 4; ++k) a += h[k] * w2[k*64 + t];
  ch[t] = sigm(a);
}

// ---- fused node chmul + rowpool(LDS) + spatial conv + nf/gin write
__global__ __launch_bounds__(256) void k_nsp(
    float* __restrict__ nf, const float* __restrict__ ch,
    const float* __restrict__ cw, const float* __restrict__ cb,
    unsigned short* __restrict__ gin, int N){
  __shared__ float s_v[134*65];
  __shared__ float s_rp[134][2];
  int tid = threadIdx.x;
  int tx = tid & 63, wv = tid >> 6;
  float chl = ch[tx];
  int base = blockIdx.x * 128;
  for (int li = wv; li < 134; li += 4){
    int r = base - 3 + li;
    if (r >= 0 && r < N)
      s_v[li*65 + tx] = nf[(size_t)r*64 + tx] * chl;
  }
  __syncthreads();
  #pragma unroll
  for (int pass = 0; pass < 2; ++pass){
    int li = (tid >> 1) + pass*128;
    if (li < 134){
      int r = base - 3 + li;
      if (r >= 0 && r < N){
        const float* vb = &s_v[li*65 + (tid & 1)*32];
        float m = vb[0], s = vb[0];
        #pragma unroll 8
        for (int k = 1; k < 32; ++k){ float t = vb[k]; m = fmaxf(m, t); s += t; }
        float mo = __shfl_xor(m, 1, 64);
        float so = __shfl_xor(s, 1, 64);
        m = fmaxf(m, mo); s += so;
        if ((tid & 1) == 0){ s_rp[li][0] = m; s_rp[li][1] = s * (1.f/64.f); }
      }
    }
  }
  __syncthreads();
  for (int li = 3 + wv; li < 131; li += 4){
    int r = base - 3 + li;
    if (r >= N) continue;
    float sp = cb[0];
    #pragma unroll
    for (int t7 = 0; t7 < 7; ++t7){
      int rr = r + t7 - 3;
      if (rr >= 0 && rr < N)
        sp += cw[t7] * s_rp[li - 3 + t7][0] + cw[7 + t7] * s_rp[li - 3 + t7][1];
    }
    float nfv = s_v[li*65 + tx] * sigm(sp);
    nf[(size_t)r*64 + tx] = nfv;
    gin[(size_t)r*128 + tx] = f2bf(nfv);
  }
}

// --------------- edge column-pool over raw features (reg weights + dbuf)
__global__ __launch_bounds__(256) void k_ecol(
    const float* __restrict__ re8,
    const float* __restrict__ ew, const float* __restrict__ eb,
    unsigned* __restrict__ pmax, float* __restrict__ psum, int E2){
  __shared__ float s_re[2][1024];
  int tid = threadIdx.x;
  int tx = tid & 63, wv = tid >> 6;
  float ewr[7];
  #pragma unroll
  for (int k = 0; k < 7; ++k) ewr[k] = ew[k*64 + tx];
  float ebl = eb[tx];
  const int CHUNK = 128;
  int base0  = blockIdx.x * CHUNK;
  int stride = gridDim.x * CHUNK;
  float m = -INFINITY, s = 0.f;
  if (base0 < E2){
    int g0 = base0 * 8;
    #pragma unroll
    for (int q = 0; q < 4; ++q){
      int idx = q*256 + tid;
      int gi = g0 + idx;
      s_re[0][idx] = (gi < E2*8) ? re8[gi] : 0.f;
    }
  }
  int buf = 0;
  for (int base = base0; base < E2; base += stride){
    __syncthreads();
    int nb = base + stride;
    if (nb < E2){
      int g0 = nb * 8;
      #pragma unroll
      for (int q = 0; q < 4; ++q){
        int idx = q*256 + tid;
        int gi = g0 + idx;
        s_re[buf ^ 1][idx] = (gi < E2*8) ? re8[gi] : 0.f;
      }
    }
    const float* sb = s_re[buf];
    #pragma unroll
    for (int j = 0; j < 32; ++j){
      int e = base + wv*32 + j;
      if (e < E2){
        const float* r = &sb[(wv*32 + j)*8];
        float v = ebl;
        #pragma unroll
        for (int k = 0; k < 7; ++k) v += r[k] * ewr[k];
        v = fmaxf(v, 0.f);
        m = fmaxf(m, v); s += v;
      }
    }
    buf ^= 1;
  }
  __shared__ float sm[4][64], ss[4][64];
  sm[wv][tx] = m; ss[wv][tx] = s;
  __syncthreads();
  if (wv == 0){
    #pragma unroll
    for (int k = 1; k < 4; ++k){ m = fmaxf(m, sm[k][tx]); s += ss[k][tx]; }
    atomicMax(&pmax[tx], fenc(m));
    atomicAdd(&psum[tx], s);
  }
}

// --- fused edge feature + rowpool(LDS) + spatial sigmoid + ef0/se store
__global__ __launch_bounds__(256) void k_erp3(
    const float* __restrict__ re8, const int* __restrict__ epos,
    const float* __restrict__ ew, const float* __restrict__ eb,
    const float* __restrict__ ch,
    const float* __restrict__ ccw, const float* __restrict__ ccb,
    unsigned short* __restrict__ ef0, float* __restrict__ se, int E2){
  __shared__ float s_re[134*8];
  __shared__ float s_v[134*65];
  __shared__ float s_rp[134][2];
  __shared__ int   s_ep[128];
  int tid = threadIdx.x;
  int tx = tid & 63, wv = tid >> 6;
  float ewr[7];
  #pragma unroll
  for (int k = 0; k < 7; ++k) ewr[k] = ew[k*64 + tx];
  float ebl = eb[tx], chl = ch[tx];
  int base = blockIdx.x * 128;
  for (int idx = tid; idx < 134*8; idx += 256){
    int li = idx >> 3, k = idx & 7;
    int e = base - 3 + li;
    s_re[idx] = (e >= 0 && e < E2) ? re8[(size_t)e*8 + k] : 0.f;
  }
  if (tid < 128 && base + tid < E2) s_ep[tid] = epos[base + tid];
  __syncthreads();
  for (int li = wv; li < 134; li += 4){
    int e = base - 3 + li;
    if (e < 0 || e >= E2) continue;
    const float* r = &s_re[li*8];
    float v = ebl;
    #pragma unroll
    for (int k = 0; k < 7; ++k) v += r[k] * ewr[k];
    v = fmaxf(v, 0.f) * chl;
    s_v[li*65 + tx] = v;
    if (li >= 3 && li < 131)
      ef0[(size_t)s_ep[li - 3]*64 + tx] = f2bf(v);
  }
  __syncthreads();
  #pragma unroll
  for (int pass = 0; pass < 2; ++pass){
    int li = (tid >> 1) + pass*128;
    if (li < 134){
      int e = base - 3 + li;
      if (e >= 0 && e < E2){
        const float* vb = &s_v[li*65 + (tid & 1)*32];
        float m = vb[0], s = vb[0];
        #pragma unroll 8
        for (int k = 1; k < 32; ++k){ float t = vb[k]; m = fmaxf(m, t); s += t; }
        float mo = __shfl_xor(m, 1, 64);
        float so = __shfl_xor(s, 1, 64);
        m = fmaxf(m, mo); s += so;
        if ((tid & 1) == 0){ s_rp[li][0] = m; s_rp[li][1] = s * (1.f/64.f); }
      }
    }
  }
  __syncthreads();
  if (tid < 128){
    int e = base + tid;
    if (e < E2){
      float sp = ccb[0];
      #pragma unroll
      for (int t7 = 0; t7 < 7; ++t7){
        int rr = e + t7 - 3;
        if (rr >= 0 && rr < E2)
          sp += ccw[t7] * s_rp[tid + t7][0] + ccw[7 + t7] * s_rp[tid + t7][1];
      }
      se[s_ep[tid]] = sigm(sp);
    }
  }
}

// ------------- agg0 = streamed sum(se*ef0) over CSR + fused concat-LN comb0
__global__ void k_aggb(const unsigned short* __restrict__ ef0, const float* __restrict__ se,
                       const int* __restrict__ rowptr, const float* __restrict__ nf,
                       const float* __restrict__ g, const float* __restrict__ b,
                       float* __restrict__ agg, unsigned short* __restrict__ comb, int N){
  int n = blockIdx.x*4 + (threadIdx.x >> 6);
  if (n >= N) return;
  int l = threadIdx.x & 63;
  int lo = rowptr[n], hi = rowptr[n+1];
  float acc = 0.f;
  int i = lo;
  for (; i + 8 <= hi; i += 8){
    float sv[8], ev[8];
    #pragma unroll
    for (int j = 0; j < 8; ++j) sv[j] = se[i + j];
    #pragma unroll
    for (int j = 0; j < 8; ++j) ev[j] = bf2f(ef0[(size_t)(i + j)*64 + l]);
    #pragma unroll
    for (int j = 0; j < 8; ++j) acc += sv[j] * ev[j];
  }
  for (; i < hi; ++i) acc += se[i] * bf2f(ef0[(size_t)i*64 + l]);
  agg[(size_t)n*64 + l] = acc;
  float a = nf[(size_t)n*64 + l];
  float v0 = a, v1 = acc - a;
  float mean = wave_sum(v0 + v1) * (1.f/128.f);
  float d0 = v0 - mean, d1 = v1 - mean;
  float var = wave_sum(d0*d0 + d1*d1) * (1.f/128.f);
  float rs = rsqrtf(var + 1e-5f);
  comb[(size_t)n*128 + l]      = f2bf(d0 * rs * g[l]      + b[l]);
  comb[(size_t)n*128 + 64 + l] = f2bf(d1 * rs * g[64 + l] + b[64 + l]);
}

// ------------------------------- coalesced LDS-transpose weight packs
__global__ __launch_bounds__(256) void k_packT1(
    const float* __restrict__ Wq, const float* __restrict__ Wk,
    const float* __restrict__ Wv, const float* __restrict__ Ws,
    unsigned short* __restrict__ Bt){
  __shared__ float t[64][65];
  int bx = blockIdx.x, by = blockIdx.y, bz = blockIdx.z;
  const float* W = (bz == 0) ? Wq : (bz == 1) ? Wk : (bz == 2) ? Wv : Ws;
  int tx = threadIdx.x & 63, ty = threadIdx.x >> 6;
  int R0 = by*64, C0 = bx*64;
  for (int r = ty; r < 64; r += 4)
    t[r][tx] = W[(size_t)(R0 + r)*256 + C0 + tx];
  __syncthreads();
  int iter = by >> 1, kr0 = (by & 1)*64;
  for (int r = ty; r < 64; r += 4)
    Bt[(size_t)iter*1024*128 + (size_t)(bz*256 + C0 + r)*128 + kr0 + tx] = f2bf(t[tx][r]);
}

__global__ __launch_bounds__(256) void k_packT2(
    const float* __restrict__ Wn, const float* __restrict__ We,
    unsigned short* __restrict__ Bt2){
  __shared__ float t[64][65];
  int by = blockIdx.y, bz = blockIdx.z;
  const float* W = (bz == 0) ? Wn : We;
  int tx = threadIdx.x & 63, ty = threadIdx.x >> 6;
  int R0 = by*64;
  for (int r = ty; r < 64; r += 4)
    t[r][tx] = W[(size_t)(R0 + r)*64 + tx];
  __syncthreads();
  int iter = by >> 2, kr0 = (by & 3)*64;
  for (int r = ty; r < 64; r += 4)
    Bt2[(size_t)iter*128*256 + (size_t)(bz*64 + r)*256 + kr0 + tx] = f2bf(t[tx][r]);
}

// gate weight pack
__global__ void k_packG(const float* __restrict__ gfw, unsigned short* __restrict__ BtG){
  int b = blockIdx.x;
  int iter = b >> 7, col = b & 127;
  int k = threadIdx.x;
  unsigned short v = 0;
  if (col < 64) v = f2bf(gfw[(size_t)iter*128*64 + (size_t)k*64 + col]);
  BtG[(size_t)b*128 + k] = v;
}

__global__ void k_biasp(const float* __restrict__ bq, const float* __restrict__ bk,
                        const float* __restrict__ bv, const float* __restrict__ bs,
                        const float* __restrict__ pnb, const float* __restrict__ gfb,
                        float* __restrict__ bias, float* __restrict__ bias2,
                        float* __restrict__ bias3){
  int i = blockIdx.x, t = threadIdx.x;
  const float* bb = (t < 256) ? bq : (t < 512) ? bk : (t < 768) ? bv : bs;
  bias[i*1024 + t] = bb[i*256 + (t & 255)];
  if (t < 64){
    bias2[i*128 + t] = pnb[i*64 + t];
    bias3[i*128 + t] = gfb[i*64 + t];
  } else if (t < 128){
    bias2[i*128 + t] = 0.f;
    bias3[i*128 + t] = 0.f;
  }
}

__global__ void k_packC(const float* __restrict__ cw1, float* __restrict__ Wp){
  int idx = blockIdx.x * blockDim.x + threadIdx.x;
  if (idx >= 64*128) return;
  int k = idx >> 7, j = idx & 127;
  Wp[idx] = (j < 64) ? cw1[k*64 + j] : cw1[(64 + k)*64 + (j - 64)];
}

// ---------------------------------------------------------- MFMA bf16 GEMM
// BM=64-row tiles; A staged in LDS (16 KB); B fragments direct from L2.
// MODE 0: cols 0-255 -> qs[gr][c] bf16; 256-511 -> kv[gr][c]; 512-767 ->
//         kv[gr][256+c]; 768-1023 -> qs[gr][256+c] bf16. (row strides 512)
// MODE 1: pnP f32 [M,128]; also writes bf16(pn) to gin[:,64:128] for cols<64
// MODE 2: gate_arg f32 [M,64] (only cols<64 stored)
template<int NSTEPS, int MODE>
__global__ __launch_bounds__(256) void k_mfma(
    const unsigned short* __restrict__ A, int lda,
    const unsigned short* __restrict__ Bt, int ldb,
    const float* __restrict__ bias,
    float* __restrict__ o_f0, unsigned short* __restrict__ o_h0,
    unsigned short* __restrict__ o_h1, int M){
  __shared__ char ldsA[16384];
  int tid = threadIdx.x;
  int nbase = blockIdx.x * 128;
  int mbase = blockIdx.y * 64;
  int l = tid & 63, wid = tid >> 6;
  int wm = (wid & 1) * 32, wn = (wid >> 1) * 64;
  f32x4 acc[2][4] = {};
  const char* Ab  = (const char*)A;
  const char* Btb = (const char*)Bt;
  for (int ks = 0; ks < NSTEPS; ++ks){
    #pragma unroll
    for (int it = 0; it < 4; ++it){
      int c = tid + it*256;
      int row = c >> 4;
      int kb = (c & 15) << 4;
      int off = (row << 8) + (kb ^ ((row & 7) << 4));
      uint4 va = make_uint4(0,0,0,0);
      int gr = mbase + row;
      if (gr < M)
        va = *reinterpret_cast<const uint4*>(Ab + (size_t)gr*(lda*2) + ks*256 + kb);
      *reinterpret_cast<uint4*>(ldsA + off) = va;
    }
    __syncthreads();
    #pragma unroll
    for (int kk = 0; kk < 4; ++kk){
      int kbyte = kk*64 + (l >> 4)*16;
      short8 af[2], bf[4];
      #pragma unroll
      for (int n = 0; n < 4; ++n){
        int fc = wn + n*16 + (l & 15);
        bf[n] = *reinterpret_cast<const short8*>(
                  Btb + (size_t)(nbase + fc)*(ldb*2) + ks*256 + kbyte);
      }
      #pragma unroll
      for (int m = 0; m < 2; ++m){
        int fr = wm + m*16 + (l & 15);
        af[m] = *reinterpret_cast<const short8*>(ldsA + (fr << 8) + (kbyte ^ ((fr & 7) << 4)));
      }
      #pragma unroll
      for (int m = 0; m < 2; ++m)
        #pragma unroll
        for (int n = 0; n < 4; ++n)
          acc[m][n] = __builtin_amdgcn_mfma_f32_16x16x32_bf16(af[m], bf[n], acc[m][n], 0, 0, 0);
    }
    __syncthreads();
  }
  #pragma unroll
  for (int n = 0; n < 4; ++n){
    int gcol = nbase + wn + n*16 + (l & 15);
    float bv = bias ? bias[gcol] : 0.f;
    #pragma unroll
    for (int m = 0; m < 2; ++m){
      int grow = mbase + wm + m*16 + (l >> 4)*4;
      #pragma unroll
      for (int r = 0; r < 4; ++r){
        int gr = grow + r;
        if (gr < M){
          float val = acc[m][n][r] + bv;
          if (MODE == 1){
            o_f0[(size_t)gr*128 + gcol] = val;
            if (gcol < 64) o_h0[(size_t)gr*128 + 64 + gcol] = f2bf(val);
          } else if (MODE == 2){
            if (gcol < 64) o_f0[(size_t)gr*64 + gcol] = val;
          } else {
            int seg = gcol >> 8, c = gcol & 255;
            if      (seg == 0) o_h1[(size_t)gr*512 + c] = f2bf(val);
            else if (seg == 1) o_h0[(size_t)gr*512 + c] = f2bf(val);
            else if (seg == 2) o_h0[(size_t)gr*512 + 256 + c] = f2bf(val);
            else               o_h1[(size_t)gr*512 + 256 + c] = f2bf(val);
          }
        }
      }
    }
  }
}

// -------------- single-pass fused attention + skip + LN (lane-partitioned)
// qs[n][0:256]=Q bf16, qs[n][256:512]=S bf16; kv[n][0:256]=K, [256:512]=V
__global__ void k_attn(const unsigned short* __restrict__ qs,
                       const unsigned short* __restrict__ kv,
                       const int* __restrict__ rowptr, const int* __restrict__ csrc,
                       const float* __restrict__ ltg, const float* __restrict__ ltb,
                       unsigned short* __restrict__ outb, int N){
  int n = blockIdx.x*4 + (threadIdx.x >> 6);
  if (n >= N) return;
  int l = threadIdx.x & 63;
  int lo = rowptr[n], hi = rowptr[n+1];
  const int l4 = l*4;
  ushort4 qu = *reinterpret_cast<const ushort4*>(qs + (size_t)n*512 + l4);
  float4 qv = make_float4(bf2f(qu.x)*0.125f, bf2f(qu.y)*0.125f,
                          bf2f(qu.z)*0.125f, bf2f(qu.w)*0.125f);
  float o0 = 0.f, o1 = 0.f, o2 = 0.f, o3 = 0.f, s = 0.f;
  int i = lo;
  for (; i + 16 <= hi; i += 16){
    ushort4 kk[16], vv[16];
    #pragma unroll
    for (int j = 0; j < 16; ++j){
      const unsigned short* row = kv + (size_t)csrc[i + j]*512 + l4;
      kk[j] = *reinterpret_cast<const ushort4*>(row);
      vv[j] = *reinterpret_cast<const ushort4*>(row + 256);
    }
    float a[16];
    #pragma unroll
    for (int j = 0; j < 16; ++j)
      a[j] = qv.x*bf2f(kk[j].x) + qv.y*bf2f(kk[j].y) + qv.z*bf2f(kk[j].z) + qv.w*bf2f(kk[j].w);
    #pragma unroll
    for (int m = 1; m < 16; m <<= 1){
      #pragma unroll
      for (int j = 0; j < 16; ++j) a[j] += __shfl_xor(a[j], m, 64);
    }
    #pragma unroll
    for (int j = 0; j < 16; ++j){
      float w = __expf(a[j]);
      s += w;
      o0 += w*bf2f(vv[j].x); o1 += w*bf2f(vv[j].y);
      o2 += w*bf2f(vv[j].z); o3 += w*bf2f(vv[j].w);
    }
  }
  for (; i + 8 <= hi; i += 8){
    ushort4 kk[8], vv[8];
    #pragma unroll
    for (int j = 0; j < 8; ++j){
      const unsigned short* row = kv + (size_t)csrc[i + j]*512 + l4;
      kk[j] = *reinterpret_cast<const ushort4*>(row);
      vv[j] = *reinterpret_cast<const ushort4*>(row + 256);
    }
    float a[8];
    #pragma unroll
    for (int j = 0; j < 8; ++j)
      a[j] = qv.x*bf2f(kk[j].x) + qv.y*bf2f(kk[j].y) + qv.z*bf2f(kk[j].z) + qv.w*bf2f(kk[j].w);
    #pragma unroll
    for (int m = 1; m < 16; m <<= 1){
      #pragma unroll
      for (int j = 0; j < 8; ++j) a[j] += __shfl_xor(a[j], m, 64);
    }
    #pragma unroll
    for (int j = 0; j < 8; ++j){
      float w = __expf(a[j]);
      s += w;
      o0 += w*bf2f(vv[j].x); o1 += w*bf2f(vv[j].y);
      o2 += w*bf2f(vv[j].z); o3 += w*bf2f(vv[j].w);
    }
  }
  for (; i < hi; ++i){
    const unsigned short* row = kv + (size_t)csrc[i]*512 + l4;
    ushort4 kk = *reinterpret_cast<const ushort4*>(row);
    ushort4 vv = *reinterpret_cast<const ushort4*>(row + 256);
    float a = qv.x*bf2f(kk.x) + qv.y*bf2f(kk.y) + qv.z*bf2f(kk.z) + qv.w*bf2f(kk.w);
    #pragma unroll
    for (int m = 1; m < 16; m <<= 1) a += __shfl_xor(a, m, 64);
    float w = __expf(a);
    s += w;
    o0 += w*bf2f(vv.x); o1 += w*bf2f(vv.y); o2 += w*bf2f(vv.z); o3 += w*bf2f(vv.w);
  }
  ushort4 su = *reinterpret_cast<const ushort4*>(qs + (size_t)n*512 + 256 + l4);
  float tx0 = bf2f(su.x), tx1 = bf2f(su.y), tx2 = bf2f(su.z), tx3 = bf2f(su.w);
  if (hi > lo){
    float r = 1.f / s;
    tx0 += o0*r; tx1 += o1*r; tx2 += o2*r; tx3 += o3*r;
  }
  float mean = wave_sum(tx0 + tx1 + tx2 + tx3) * (1.f/256.f);
  float dx = tx0 - mean, dy = tx1 - mean, dz = tx2 - mean, dw = tx3 - mean;
  float var = wave_sum(dx*dx + dy*dy + dz*dz + dw*dw) * (1.f/256.f);
  float rs = rsqrtf(var + 1e-5f);
  float4 g = *reinterpret_cast<const float4*>(ltg + l4);
  float4 b = *reinterpret_cast<const float4*>(ltb + l4);
  ushort4 o;
  o.x = f2bf(dx*rs*g.x + b.x);
  o.y = f2bf(dy*rs*g.y + b.y);
  o.z = f2bf(dz*rs*g.z + b.z);
  o.w = f2bf(dw*rs*g.w + b.w);
  *reinterpret_cast<ushort4*>(outb + (size_t)n*256 + l4) = o;
}

// ------ gated fusion (gate precomputed by MFMA) + agg update + comb-LN
__global__ __launch_bounds__(256) void k_gate2(
    float* __restrict__ nf, float* __restrict__ agg,
    const float* __restrict__ pnP, const float* __restrict__ gate_arg,
    const int* __restrict__ rowptr, const int* __restrict__ csrc,
    const float* __restrict__ peb,
    const float* __restrict__ cg, const float* __restrict__ cbv,
    unsigned short* __restrict__ comb, unsigned short* __restrict__ gin,
    int doComb, int N){
  int n = blockIdx.x*4 + (threadIdx.x >> 6);
  if (n >= N) return;
  int l = threadIdx.x & 63;
  float g = sigm(gate_arg[(size_t)n*64 + l]);
  float nfv = nf[(size_t)n*64 + l];
  float pnv = pnP[(size_t)n*128 + l];
  float nfn = nfv * (1.f + g) + pnv * (1.f - g);
  nf[(size_t)n*64 + l] = nfn;
  gin[(size_t)n*128 + l] = f2bf(nfn);
  int lo = rowptr[n], hi = rowptr[n+1];
  float sp = 0.f;
  int i = lo;
  for (; i + 8 <= hi; i += 8){
    float pv[8];
    #pragma unroll
    for (int j = 0; j < 8; ++j)
      pv[j] = pnP[(size_t)csrc[i+j]*128 + 64 + l];
    #pragma unroll
    for (int j = 0; j < 8; ++j) sp += pv[j];
  }
  for (; i < hi; ++i) sp += pnP[(size_t)csrc[i]*128 + 64 + l];
  float Pn = pnP[(size_t)n*128 + 64 + l];
  float aggn = agg[(size_t)n*64 + l] + sp - (float)(hi - lo) * (Pn - peb[l]);
  agg[(size_t)n*64 + l] = aggn;
  if (doComb){
    float v0 = nfn, v1 = aggn - nfn;
    float mean = wave_sum(v0 + v1) * (1.f/128.f);
    float d0 = v0 - mean, d1 = v1 - mean;
    float var = wave_sum(d0*d0 + d1*d1) * (1.f/128.f);
    float rs = rsqrtf(var + 1e-5f);
    comb[(size_t)n*128 + l]      = f2bf(d0 * rs * cg[l]      + cbv[l]);
    comb[(size_t)n*128 + 64 + l] = f2bf(d1 * rs * cg[64 + l] + cbv[64 + l]);
  }
}

// ------------------------------------------------------------- classifier
template<int K, int BN>
__global__ __launch_bounds__(256) void k_gemm(
    const float* __restrict__ in, const float* __restrict__ W, int ldw,
    const float* __restrict__ bias, float* __restrict__ out, int ldo, int nrows){
  constexpr int PAD = BN + 4;
  __shared__ float s_in[K * PAD];
  int n0 = blockIdx.x * BN;
  int tid = threadIdx.x;
  for (int idx = tid; idx < BN * K; idx += 256){
    int r = idx / K, k = idx - r * K;
    float v = (n0 + r < nrows) ? in[(size_t)(n0 + r) * K + k] : 0.f;
    s_in[k * PAD + r] = v;
  }
  __syncthreads();
  int tx = tid & 15, ty = tid >> 4;
  constexpr int NT = BN / 16;
  int col0 = blockIdx.y * 64 + tx * 4;
  float acc[NT][4] = {};
  for (int k = 0; k < K; ++k){
    const float4 wv = *reinterpret_cast<const float4*>(&W[(size_t)k * ldw + col0]);
    #pragma unroll
    for (int i = 0; i < NT; ++i){
      float cv = s_in[k * PAD + ty * NT + i];
      acc[i][0] += cv * wv.x;
      acc[i][1] += cv * wv.y;
      acc[i][2] += cv * wv.z;
      acc[i][3] += cv * wv.w;
    }
  }
  #pragma unroll
  for (int i = 0; i < NT; ++i){
    int n = n0 + ty * NT + i;
    if (n < nrows){
      float4 o = make_float4(acc[i][0], acc[i][1], acc[i][2], acc[i][3]);
      *reinterpret_cast<float4*>(&out[(size_t)n * ldo + col0]) = o;
    }
  }
}

__global__ void k_final(const float* __restrict__ AB,
                        const int* __restrict__ ei, const float* __restrict__ cb1,
                        const float* __restrict__ cw2, const float* __restrict__ cb2,
                        float* __restrict__ dout, int E){
  int e = blockIdx.x*4 + (threadIdx.x >> 6);
  if (e >= E) return;
  int l = threadIdx.x & 63;
  int i0 = ei[e], i1 = ei[E + e];
  float h = fmaxf(AB[(size_t)i0*128 + l] + AB[(size_t)i1*128 + 64 + l] + cb1[l], 0.f);
  float p = wave_sum(h * cw2[l]);
  if (l == 0) dout[e] = p + cb2[0];
}

// ===========================================================================
extern "C" void kernel_launch(void* const* d_in, const int* in_sizes, int n_in,
                              void* d_out, int out_size, void* d_ws, size_t ws_size,
                              hipStream_t stream){
  const float* x         = (const float*)d_in[0];
  const float* edge_attr = (const float*)d_in[1];
  const float* node_w    = (const float*)d_in[2];
  const float* node_b    = (const float*)d_in[3];
  const float* edge_w    = (const float*)d_in[4];
  const float* edge_b    = (const float*)d_in[5];
  const float* z_emb     = (const float*)d_in[6];
  const float* cn_w1     = (const float*)d_in[7];
  const float* cn_b1     = (const float*)d_in[8];
  const float* cn_w2     = (const float*)d_in[9];
  const float* cn_b2     = (const float*)d_in[10];
  const float* cn_cw     = (const float*)d_in[11];
  const float* cn_cb     = (const float*)d_in[12];
  const float* ce_w1     = (const float*)d_in[13];
  const float* ce_b1     = (const float*)d_in[14];
  const float* ce_w2     = (const float*)d_in[15];
  const float* ce_b2     = (const float*)d_in[16];
  const float* ce_cw     = (const float*)d_in[17];
  const float* ce_cb     = (const float*)d_in[18];
  const float* Wq        = (const float*)d_in[19];
  const float* bq        = (const float*)d_in[20];
  const float* Wk        = (const float*)d_in[21];
  const float* bk        = (const float*)d_in[22];
  const float* Wv        = (const float*)d_in[23];
  const float* bv        = (const float*)d_in[24];
  const float* Ws        = (const float*)d_in[25];
  const float* bs        = (const float*)d_in[26];
  const float* lt_g      = (const float*)d_in[27];
  const float* lt_b      = (const float*)d_in[28];
  const float* lc_g      = (const float*)d_in[29];
  const float* lc_b      = (const float*)d_in[30];
  const float* pe_w      = (const float*)d_in[31];
  const float* pe_b      = (const float*)d_in[32];
  const float* pn_w      = (const float*)d_in[33];
  const float* pn_b      = (const float*)d_in[34];
  const float* gf_w      = (const float*)d_in[35];
  const float* gf_b      = (const float*)d_in[36];
  const float* c_w1      = (const float*)d_in[37];
  const float* c_b1      = (const float*)d_in[38];
  const float* c_w2      = (const float*)d_in[39];
  const float* c_b2      = (const float*)d_in[40];
  const int*   edge_index= (const int*)d_in[41];

  const int N  = in_sizes[0] / 6;
  const int E  = in_sizes[1] / 4;
  const int E2 = 2 * E;

  // ---------------- workspace layout
  char* p = (char*)d_ws;
  auto alloc = [&](size_t bytes)->char*{
    char* r = p; p += (bytes + 255) & ~(size_t)255; return r;
  };
  char* zbase = p;
  int*            w_deg    = (int*)           alloc((size_t)N * 4);
  int*            w_cur    = (int*)           alloc((size_t)N * 4);
  unsigned*       w_pmax   = (unsigned*)      alloc(64 * 4);
  float*          w_psum   = (float*)         alloc(64 * 4);
  unsigned*       w_pmax2  = (unsigned*)      alloc(64 * 4);
  float*          w_psum2  = (float*)         alloc(64 * 4);
  size_t zbytes = (size_t)(p - zbase);
  int*            w_src    = (int*)           alloc((size_t)E2 * 4);
  int*            w_dst    = (int*)           alloc((size_t)E2 * 4);
  int*            w_rowptr = (int*)           alloc((size_t)(N + 1) * 4);
  int*            w_csrc   = (int*)           alloc((size_t)E2 * 4);
  int*            w_epos   = (int*)           alloc((size_t)E2 * 4);
  float*          w_re8    = (float*)         alloc((size_t)E2 * 8 * 4);
  float*          w_nf     = (float*)         alloc((size_t)N * 64 * 4);
  float*          w_agg    = (float*)         alloc((size_t)N * 64 * 4);
  unsigned short* w_ef0    = (unsigned short*)alloc((size_t)E2 * 64 * 2);
  float*          w_se     = (float*)         alloc((size_t)E2 * 4);
  unsigned short* w_comb   = (unsigned short*)alloc((size_t)N * 128 * 2);
  unsigned short* w_gin    = (unsigned short*)alloc((size_t)N * 128 * 2);
  float*          w_gate   = (float*)         alloc((size_t)N * 64 * 4);
  unsigned short* w_qs     = (unsigned short*)alloc((size_t)N * 512 * 2);
  unsigned short* w_kv     = (unsigned short*)alloc((size_t)N * 512 * 2);
  unsigned short* w_outb   = (unsigned short*)alloc((size_t)N * 256 * 2);
  float*          w_pnP    = (float*)         alloc((size_t)N * 128 * 4);
  float*          w_AB     = (float*)         alloc((size_t)N * 128 * 4);
  float*          w_Wp     = (float*)         alloc((size_t)64 * 128 * 4);
  unsigned short* w_Bt     = (unsigned short*)alloc((size_t)3 * 1024 * 128 * 2);
  float*          w_bias   = (float*)         alloc((size_t)3 * 1024 * 4);
  unsigned short* w_Bt2    = (unsigned short*)alloc((size_t)3 * 128 * 256 * 2);
  float*          w_bias2  = (float*)         alloc((size_t)3 * 128 * 4);
  unsigned short* w_BtG    = (unsigned short*)alloc((size_t)3 * 128 * 128 * 2);
  float*          w_bias3  = (float*)         alloc((size_t)3 * 128 * 4);
  float*          w_ch     = (float*)         alloc(64 * 4);
  float*          w_ch2    = (float*)         alloc(64 * 4);

  hipMemsetAsync(zbase, 0, zbytes, stream);

  // ---------------- CSR + raw-edge gather + node embedding/CBAM
  k_build_edges<<<(E2 + 255)/256, 256, 0, stream>>>(edge_index, E2, E, w_src, w_dst, w_deg);
  k_scan<<<1, 1024, 0, stream>>>(w_deg, w_rowptr, N);
  k_fill<<<(E2 + 255)/256, 256, 0, stream>>>(w_src, w_dst, w_rowptr, w_cur, w_csrc, w_epos,
                                             x, edge_attr, w_re8, E2, E);
  k_embed_pool<<<256, 256, 0, stream>>>(x, node_w, node_b, z_emb, w_nf, w_pmax, w_psum, N);
  k_cbam_mlp<<<1, 64, 0, stream>>>(w_pmax, w_psum, 1.f/(float)N,
                                   cn_w1, cn_b1, cn_w2, cn_b2, w_ch);
  k_nsp<<<(N + 127)/128, 256, 0, stream>>>(w_nf, w_ch, cn_cw, cn_cb, w_gin, N);

  // ---------------- edge CBAM (streamed) -> ef0/se (CSR order) -> agg0 + comb0
  k_ecol<<<256, 256, 0, stream>>>(w_re8, edge_w, edge_b, w_pmax2, w_psum2, E2);
  k_cbam_mlp<<<1, 64, 0, stream>>>(w_pmax2, w_psum2, 1.f/(float)E2,
                                   ce_w1, ce_b1, ce_w2, ce_b2, w_ch2);
  k_erp3<<<(E2 + 127)/128, 256, 0, stream>>>(w_re8, w_epos, edge_w, edge_b, w_ch2,
                                             ce_cw, ce_cb, w_ef0, w_se, E2);
  k_aggb<<<(N + 3)/4, 256, 0, stream>>>(w_ef0, w_se, w_rowptr, w_nf,
                                        lc_g, lc_b, w_agg, w_comb, N);

  // ---------------- pack all iteration weights
  k_packT1<<<dim3(4, 6, 4), 256, 0, stream>>>(Wq, Wk, Wv, Ws, w_Bt);
  k_packT2<<<dim3(1, 12, 2), 256, 0, stream>>>(pn_w, pe_w, w_Bt2);
  k_packG<<<3*128, 128, 0, stream>>>(gf_w, w_BtG);
  k_biasp<<<3, 1024, 0, stream>>>(bq, bk, bv, bs, pn_b, gf_b, w_bias, w_bias2, w_bias3);
  k_packC<<<32, 256, 0, stream>>>(c_w1, w_Wp);

  // ---------------- message-passing iterations
  const int MB2 = (N + 63) / 64;
  for (int i = 0; i < 3; ++i){
    k_mfma<1,0><<<dim3(8, MB2), 256, 0, stream>>>(w_comb, 128,
                                                  w_Bt + (size_t)i*1024*128, 128,
                                                  w_bias + (size_t)i*1024,
                                                  nullptr, w_kv, w_qs, N);
    k_attn<<<(N + 3)/4, 256, 0, stream>>>(w_qs, w_kv, w_rowptr, w_csrc,
                                          lt_g + (size_t)i*256, lt_b + (size_t)i*256,
                                          w_outb, N);
    k_mfma<2,1><<<dim3(1, MB2), 256, 0, stream>>>(w_outb, 256,
                                                  w_Bt2 + (size_t)i*128*256, 256,
                                                  w_bias2 + (size_t)i*128,
                                                  w_pnP, w_gin, nullptr, N);
    k_mfma<1,2><<<dim3(1, MB2), 256, 0, stream>>>(w_gin, 128,
                                                  w_BtG + (size_t)i*128*128, 128,
                                                  w_bias3 + (size_t)i*128,
                                                  w_gate, nullptr, nullptr, N);
    int doComb = (i < 2) ? 1 : 0;
    const float* cg  = lc_g + (size_t)(i < 2 ? i+1 : 0)*128;
    const float* cbv = lc_b + (size_t)(i < 2 ? i+1 : 0)*128;
    k_gate2<<<(N + 3)/4, 256, 0, stream>>>(w_nf, w_agg, w_pnP, w_gate,
                                           w_rowptr, w_csrc,
                                           pe_b + (size_t)i*64,
                                           cg, cbv, w_comb, w_gin, doComb, N);
  }

  // ---------------- classifier (fused A|B GEMM, then edge head)
  dim3 gAB((N + 63)/64, 2);
  k_gemm<64,64><<<gAB, 256, 0, stream>>>(w_nf, w_Wp, 128, nullptr, w_AB, 128, N);
  k_final<<<(E + 3)/4, 256, 0, stream>>>(w_AB, edge_index, c_b1, c_w2, c_b2,
                                         (float*)d_out, E);
}

// Round 17
// 692.146 us; speedup vs baseline: 1.0264x; 1.0264x over previous
//
#include <hip/hip_runtime.h>
#include <math.h>

typedef __attribute__((ext_vector_type(8))) short short8;
typedef __attribute__((ext_vector_type(4))) float f32x4;

// ---------------------------------------------------------------- utilities
__device__ __forceinline__ float wave_sum(float v){
  #pragma unroll
  for (int m = 32; m; m >>= 1) v += __shfl_xor(v, m, 64);
  return v;
}
__device__ __forceinline__ unsigned fenc(float f){
  unsigned u = __float_as_uint(f);
  return (u >> 31) ? ~u : (u | 0x80000000u);
}
__device__ __forceinline__ float fdec(unsigned e){
  return (e >> 31) ? __uint_as_float(e & 0x7fffffffu) : __uint_as_float(~e);
}
__device__ __forceinline__ float sigm(float x){ return 1.f / (1.f + __expf(-x)); }
__device__ __forceinline__ unsigned short f2bf(float f){
  union { float f; unsigned u; } x; x.f = f;
  unsigned r = x.u + 0x7fffu + ((x.u >> 16) & 1u);
  return (unsigned short)(r >> 16);
}
__device__ __forceinline__ float bf2f(unsigned short h){
  union { unsigned u; float f; } x; x.u = ((unsigned)h) << 16;
  return x.f;
}

// ------------------------------------------------------------ CSR building
__global__ void k_build_edges(const int* __restrict__ ei, int E2, int E,
                              int* __restrict__ src, int* __restrict__ dst,
                              int* __restrict__ deg){
  int e = blockIdx.x * blockDim.x + threadIdx.x;
  if (e >= E2) return;
  int s = ei[e];
  int d = (e < E) ? ei[e + E] : ei[e - E];
  src[e] = s; dst[e] = d;
  atomicAdd(&deg[d], 1);
}

__global__ void k_scan(const int* __restrict__ deg, int* __restrict__ rowptr, int N){
  __shared__ int part[1024];
  int t = threadIdx.x;
  int chunk = (N + 1023) / 1024;
  int lo = t * chunk, hi = lo + chunk; if (hi > N) hi = N;
  int s = 0;
  for (int i = lo; i < hi; ++i) s += deg[i];
  part[t] = s;
  __syncthreads();
  for (int off = 1; off < 1024; off <<= 1){
    int v = (t >= off) ? part[t - off] : 0;
    __syncthreads();
    part[t] += v;
    __syncthreads();
  }
  int run = part[t] - s;
  for (int i = lo; i < hi; ++i){ rowptr[i] = run; run += deg[i]; }
  if (t == 1023) rowptr[N] = part[1023];
}

// fill CSR + gather raw edge features once (edge-per-lane, lane-parallel)
__global__ void k_fill(const int* __restrict__ src, const int* __restrict__ dst,
                       const int* __restrict__ rowptr,
                       int* __restrict__ cur, int* __restrict__ csrc,
                       int* __restrict__ epos,
                       const float* __restrict__ x, const float* __restrict__ ea,
                       float* __restrict__ re8, int E2, int E){
  int e = blockIdx.x * blockDim.x + threadIdx.x;
  if (e >= E2) return;
  int s = src[e], d = dst[e];
  int pos = rowptr[d] + atomicAdd(&cur[d], 1);
  csrc[pos] = s;
  epos[e] = pos;
  int row = (e < E) ? e : e - E;
  float4 eav = *reinterpret_cast<const float4*>(ea + (size_t)row*4);
  float r0 = x[s*6]     - x[d*6];
  float r1 = x[s*6 + 1] - x[d*6 + 1];
  float r2 = x[s*6 + 2] - x[d*6 + 2];
  *reinterpret_cast<float4*>(re8 + (size_t)e*8)     = eav;
  *reinterpret_cast<float4*>(re8 + (size_t)e*8 + 4) = make_float4(r0, r1, r2, 0.f);
}

// ------------------------- fused node embedding + column pool (max/mean)
__global__ void k_embed_pool(const float* __restrict__ x, const float* __restrict__ nw,
                             const float* __restrict__ nb, const float* __restrict__ zemb,
                             float* __restrict__ nf,
                             unsigned* __restrict__ pmax, float* __restrict__ psum, int N){
  int tx = threadIdx.x & 63;
  int ty = threadIdx.x >> 6;
  const float allowed[6] = {8.f, 23.f, 39.f, 54.f, 90.f, 180.f};
  float m = -INFINITY, s = 0.f;
  for (int n = blockIdx.x*4 + ty; n < N; n += gridDim.x*4){
    float xv[6];
    #pragma unroll
    for (int k = 0; k < 6; ++k) xv[k] = x[n*6 + k];
    float v = nb[tx];
    #pragma unroll
    for (int k = 0; k < 6; ++k) v += xv[k] * nw[k*64 + tx];
    v = fmaxf(v, 0.f);
    float r = rintf(xv[2]);
    int zi = 0; float bd = fabsf(r - allowed[0]);
    #pragma unroll
    for (int k = 1; k < 6; ++k){ float d = fabsf(r - allowed[k]); if (d < bd){ bd = d; zi = k; } }
    v += zemb[zi*64 + tx];
    nf[(size_t)n*64 + tx] = v;
    m = fmaxf(m, v); s += v;
  }
  __shared__ float sm[4][64], ss[4][64];
  sm[ty][tx] = m; ss[ty][tx] = s;
  __syncthreads();
  if (ty == 0){
    #pragma unroll
    for (int k = 1; k < 4; ++k){ m = fmaxf(m, sm[k][tx]); s += ss[k][tx]; }
    atomicMax(&pmax[tx], fenc(m));
    atomicAdd(&psum[tx], s);
  }
}

// ------------------------------------------------------------------- CBAM MLP
__global__ void k_cbam_mlp(const unsigned* __restrict__ pmax, const float* __restrict__ psum,
                           float invR,
                           const float* __restrict__ w1, const float* __restrict__ b1,
                           const float* __restrict__ w2, const float* __restrict__ b2,
                           float* __restrict__ ch){
  __shared__ float pool[128];
  __shared__ float h[4];
  int t = threadIdx.x;
  pool[t]      = fdec(pmax[t]);
  pool[64 + t] = psum[t] * invR;
  __syncthreads();
  if (t < 4){
    float a = b1[t];
    for (int k = 0; k < 128; ++k) a += pool[k] * w1[k*4 + t];
    h[t] = fmaxf(a, 0.f);
  }
  __syncthreads();
  float a = b2[t];
  #pragma unroll
  for (int k = 0; k < 4; ++k) a += h[k] * w2[k*64 + t];
  ch[t] = sigm(a);
}

// ---- fused node chmul + rowpool(LDS) + spatial conv + nf/gin write
__global__ __launch_bounds__(256) void k_nsp(
    float* __restrict__ nf, const float* __restrict__ ch,
    const float* __restrict__ cw, const float* __restrict__ cb,
    unsigned short* __restrict__ gin, int N){
  __shared__ float s_v[134*65];
  __shared__ float s_rp[134][2];
  int tid = threadIdx.x;
  int tx = tid & 63, wv = tid >> 6;
  float chl = ch[tx];
  int base = blockIdx.x * 128;
  for (int li = wv; li < 134; li += 4){
    int r = base - 3 + li;
    if (r >= 0 && r < N)
      s_v[li*65 + tx] = nf[(size_t)r*64 + tx] * chl;
  }
  __syncthreads();
  #pragma unroll
  for (int pass = 0; pass < 2; ++pass){
    int li = (tid >> 1) + pass*128;
    if (li < 134){
      int r = base - 3 + li;
      if (r >= 0 && r < N){
        const float* vb = &s_v[li*65 + (tid & 1)*32];
        float m = vb[0], s = vb[0];
        #pragma unroll 8
        for (int k = 1; k < 32; ++k){ float t = vb[k]; m = fmaxf(m, t); s += t; }
        float mo = __shfl_xor(m, 1, 64);
        float so = __shfl_xor(s, 1, 64);
        m = fmaxf(m, mo); s += so;
        if ((tid & 1) == 0){ s_rp[li][0] = m; s_rp[li][1] = s * (1.f/64.f); }
      }
    }
  }
  __syncthreads();
  for (int li = 3 + wv; li < 131; li += 4){
    int r = base - 3 + li;
    if (r >= N) continue;
    float sp = cb[0];
    #pragma unroll
    for (int t7 = 0; t7 < 7; ++t7){
      int rr = r + t7 - 3;
      if (rr >= 0 && rr < N)
        sp += cw[t7] * s_rp[li - 3 + t7][0] + cw[7 + t7] * s_rp[li - 3 + t7][1];
    }
    float nfv = s_v[li*65 + tx] * sigm(sp);
    nf[(size_t)r*64 + tx] = nfv;
    gin[(size_t)r*128 + tx] = f2bf(nfv);
  }
}

// --------------- edge column-pool over raw features (reg weights + dbuf)
__global__ __launch_bounds__(256) void k_ecol(
    const float* __restrict__ re8,
    const float* __restrict__ ew, const float* __restrict__ eb,
    unsigned* __restrict__ pmax, float* __restrict__ psum, int E2){
  __shared__ float s_re[2][1024];
  int tid = threadIdx.x;
  int tx = tid & 63, wv = tid >> 6;
  float ewr[7];
  #pragma unroll
  for (int k = 0; k < 7; ++k) ewr[k] = ew[k*64 + tx];
  float ebl = eb[tx];
  const int CHUNK = 128;
  int base0  = blockIdx.x * CHUNK;
  int stride = gridDim.x * CHUNK;
  float m = -INFINITY, s = 0.f;
  if (base0 < E2){
    int g0 = base0 * 8;
    #pragma unroll
    for (int q = 0; q < 4; ++q){
      int idx = q*256 + tid;
      int gi = g0 + idx;
      s_re[0][idx] = (gi < E2*8) ? re8[gi] : 0.f;
    }
  }
  int buf = 0;
  for (int base = base0; base < E2; base += stride){
    __syncthreads();
    int nb = base + stride;
    if (nb < E2){
      int g0 = nb * 8;
      #pragma unroll
      for (int q = 0; q < 4; ++q){
        int idx = q*256 + tid;
        int gi = g0 + idx;
        s_re[buf ^ 1][idx] = (gi < E2*8) ? re8[gi] : 0.f;
      }
    }
    const float* sb = s_re[buf];
    #pragma unroll
    for (int j = 0; j < 32; ++j){
      int e = base + wv*32 + j;
      if (e < E2){
        const float* r = &sb[(wv*32 + j)*8];
        float v = ebl;
        #pragma unroll
        for (int k = 0; k < 7; ++k) v += r[k] * ewr[k];
        v = fmaxf(v, 0.f);
        m = fmaxf(m, v); s += v;
      }
    }
    buf ^= 1;
  }
  __shared__ float sm[4][64], ss[4][64];
  sm[wv][tx] = m; ss[wv][tx] = s;
  __syncthreads();
  if (wv == 0){
    #pragma unroll
    for (int k = 1; k < 4; ++k){ m = fmaxf(m, sm[k][tx]); s += ss[k][tx]; }
    atomicMax(&pmax[tx], fenc(m));
    atomicAdd(&psum[tx], s);
  }
}

// --- fused edge feature + rowpool(LDS) + spatial sigmoid + ef0/se store
__global__ __launch_bounds__(256) void k_erp3(
    const float* __restrict__ re8, const int* __restrict__ epos,
    const float* __restrict__ ew, const float* __restrict__ eb,
    const float* __restrict__ ch,
    const float* __restrict__ ccw, const float* __restrict__ ccb,
    unsigned short* __restrict__ ef0, float* __restrict__ se, int E2){
  __shared__ float s_re[134*8];
  __shared__ float s_v[134*65];
  __shared__ float s_rp[134][2];
  __shared__ int   s_ep[128];
  int tid = threadIdx.x;
  int tx = tid & 63, wv = tid >> 6;
  float ewr[7];
  #pragma unroll
  for (int k = 0; k < 7; ++k) ewr[k] = ew[k*64 + tx];
  float ebl = eb[tx], chl = ch[tx];
  int base = blockIdx.x * 128;
  for (int idx = tid; idx < 134*8; idx += 256){
    int li = idx >> 3, k = idx & 7;
    int e = base - 3 + li;
    s_re[idx] = (e >= 0 && e < E2) ? re8[(size_t)e*8 + k] : 0.f;
  }
  if (tid < 128 && base + tid < E2) s_ep[tid] = epos[base + tid];
  __syncthreads();
  for (int li = wv; li < 134; li += 4){
    int e = base - 3 + li;
    if (e < 0 || e >= E2) continue;
    const float* r = &s_re[li*8];
    float v = ebl;
    #pragma unroll
    for (int k = 0; k < 7; ++k) v += r[k] * ewr[k];
    v = fmaxf(v, 0.f) * chl;
    s_v[li*65 + tx] = v;
    if (li >= 3 && li < 131)
      ef0[(size_t)s_ep[li - 3]*64 + tx] = f2bf(v);
  }
  __syncthreads();
  #pragma unroll
  for (int pass = 0; pass < 2; ++pass){
    int li = (tid >> 1) + pass*128;
    if (li < 134){
      int e = base - 3 + li;
      if (e >= 0 && e < E2){
        const float* vb = &s_v[li*65 + (tid & 1)*32];
        float m = vb[0], s = vb[0];
        #pragma unroll 8
        for (int k = 1; k < 32; ++k){ float t = vb[k]; m = fmaxf(m, t); s += t; }
        float mo = __shfl_xor(m, 1, 64);
        float so = __shfl_xor(s, 1, 64);
        m = fmaxf(m, mo); s += so;
        if ((tid & 1) == 0){ s_rp[li][0] = m; s_rp[li][1] = s * (1.f/64.f); }
      }
    }
  }
  __syncthreads();
  if (tid < 128){
    int e = base + tid;
    if (e < E2){
      float sp = ccb[0];
      #pragma unroll
      for (int t7 = 0; t7 < 7; ++t7){
        int rr = e + t7 - 3;
        if (rr >= 0 && rr < E2)
          sp += ccw[t7] * s_rp[tid + t7][0] + ccw[7 + t7] * s_rp[tid + t7][1];
      }
      se[s_ep[tid]] = sigm(sp);
    }
  }
}

// ------------- agg0 = streamed sum(se*ef0) over CSR + fused concat-LN comb0
__global__ void k_aggb(const unsigned short* __restrict__ ef0, const float* __restrict__ se,
                       const int* __restrict__ rowptr, const float* __restrict__ nf,
                       const float* __restrict__ g, const float* __restrict__ b,
                       float* __restrict__ agg, unsigned short* __restrict__ comb, int N){
  int n = blockIdx.x*4 + (threadIdx.x >> 6);
  if (n >= N) return;
  int l = threadIdx.x & 63;
  int lo = rowptr[n], hi = rowptr[n+1];
  float acc = 0.f;
  int i = lo;
  for (; i + 8 <= hi; i += 8){
    float sv[8], ev[8];
    #pragma unroll
    for (int j = 0; j < 8; ++j) sv[j] = se[i + j];
    #pragma unroll
    for (int j = 0; j < 8; ++j) ev[j] = bf2f(ef0[(size_t)(i + j)*64 + l]);
    #pragma unroll
    for (int j = 0; j < 8; ++j) acc += sv[j] * ev[j];
  }
  for (; i < hi; ++i) acc += se[i] * bf2f(ef0[(size_t)i*64 + l]);
  agg[(size_t)n*64 + l] = acc;
  float a = nf[(size_t)n*64 + l];
  float v0 = a, v1 = acc - a;
  float mean = wave_sum(v0 + v1) * (1.f/128.f);
  float d0 = v0 - mean, d1 = v1 - mean;
  float var = wave_sum(d0*d0 + d1*d1) * (1.f/128.f);
  float rs = rsqrtf(var + 1e-5f);
  comb[(size_t)n*128 + l]      = f2bf(d0 * rs * g[l]      + b[l]);
  comb[(size_t)n*128 + 64 + l] = f2bf(d1 * rs * g[64 + l] + b[64 + l]);
}

// ------------------------------- coalesced LDS-transpose weight packs
__global__ __launch_bounds__(256) void k_packT1(
    const float* __restrict__ Wq, const float* __restrict__ Wk,
    const float* __restrict__ Wv, const float* __restrict__ Ws,
    unsigned short* __restrict__ Bt){
  __shared__ float t[64][65];
  int bx = blockIdx.x, by = blockIdx.y, bz = blockIdx.z;
  const float* W = (bz == 0) ? Wq : (bz == 1) ? Wk : (bz == 2) ? Wv : Ws;
  int tx = threadIdx.x & 63, ty = threadIdx.x >> 6;
  int R0 = by*64, C0 = bx*64;
  for (int r = ty; r < 64; r += 4)
    t[r][tx] = W[(size_t)(R0 + r)*256 + C0 + tx];
  __syncthreads();
  int iter = by >> 1, kr0 = (by & 1)*64;
  for (int r = ty; r < 64; r += 4)
    Bt[(size_t)iter*1024*128 + (size_t)(bz*256 + C0 + r)*128 + kr0 + tx] = f2bf(t[tx][r]);
}

__global__ __launch_bounds__(256) void k_packT2(
    const float* __restrict__ Wn, const float* __restrict__ We,
    unsigned short* __restrict__ Bt2){
  __shared__ float t[64][65];
  int by = blockIdx.y, bz = blockIdx.z;
  const float* W = (bz == 0) ? Wn : We;
  int tx = threadIdx.x & 63, ty = threadIdx.x >> 6;
  int R0 = by*64;
  for (int r = ty; r < 64; r += 4)
    t[r][tx] = W[(size_t)(R0 + r)*64 + tx];
  __syncthreads();
  int iter = by >> 2, kr0 = (by & 3)*64;
  for (int r = ty; r < 64; r += 4)
    Bt2[(size_t)iter*128*256 + (size_t)(bz*64 + r)*256 + kr0 + tx] = f2bf(t[tx][r]);
}

// gate weight pack
__global__ void k_packG(const float* __restrict__ gfw, unsigned short* __restrict__ BtG){
  int b = blockIdx.x;
  int iter = b >> 7, col = b & 127;
  int k = threadIdx.x;
  unsigned short v = 0;
  if (col < 64) v = f2bf(gfw[(size_t)iter*128*64 + (size_t)k*64 + col]);
  BtG[(size_t)b*128 + k] = v;
}

__global__ void k_biasp(const float* __restrict__ bq, const float* __restrict__ bk,
                        const float* __restrict__ bv, const float* __restrict__ bs,
                        const float* __restrict__ pnb, const float* __restrict__ gfb,
                        float* __restrict__ bias, float* __restrict__ bias2,
                        float* __restrict__ bias3){
  int i = blockIdx.x, t = threadIdx.x;
  const float* bb = (t < 256) ? bq : (t < 512) ? bk : (t < 768) ? bv : bs;
  bias[i*1024 + t] = bb[i*256 + (t & 255)];
  if (t < 64){
    bias2[i*128 + t] = pnb[i*64 + t];
    bias3[i*128 + t] = gfb[i*64 + t];
  } else if (t < 128){
    bias2[i*128 + t] = 0.f;
    bias3[i*128 + t] = 0.f;
  }
}

__global__ void k_packC(const float* __restrict__ cw1, float* __restrict__ Wp){
  int idx = blockIdx.x * blockDim.x + threadIdx.x;
  if (idx >= 64*128) return;
  int k = idx >> 7, j = idx & 127;
  Wp[idx] = (j < 64) ? cw1[k*64 + j] : cw1[(64 + k)*64 + (j - 64)];
}

// ---------------------------------------------------------- MFMA bf16 GEMM
// BM=64-row tiles; A staged in LDS (16 KB); B fragments direct from L2.
// MODE 0: cols 0-255 -> qs[gr][c] bf16; 256-511 -> kv[gr][c]; 512-767 ->
//         kv[gr][256+c]; 768-1023 -> qs[gr][256+c] bf16. (row strides 512)
// MODE 1: pnP f32 [M,128]; bf16(pn) -> gin[:,64:128] (cols<64);
//         bf16(P)  -> Pbf[M][64]    (cols>=64)
// MODE 2: gate_arg f32 [M,64] (only cols<64 stored)
template<int NSTEPS, int MODE>
__global__ __launch_bounds__(256) void k_mfma(
    const unsigned short* __restrict__ A, int lda,
    const unsigned short* __restrict__ Bt, int ldb,
    const float* __restrict__ bias,
    float* __restrict__ o_f0, unsigned short* __restrict__ o_h0,
    unsigned short* __restrict__ o_h1, int M){
  __shared__ char ldsA[16384];
  int tid = threadIdx.x;
  int nbase = blockIdx.x * 128;
  int mbase = blockIdx.y * 64;
  int l = tid & 63, wid = tid >> 6;
  int wm = (wid & 1) * 32, wn = (wid >> 1) * 64;
  f32x4 acc[2][4] = {};
  const char* Ab  = (const char*)A;
  const char* Btb = (const char*)Bt;
  for (int ks = 0; ks < NSTEPS; ++ks){
    #pragma unroll
    for (int it = 0; it < 4; ++it){
      int c = tid + it*256;
      int row = c >> 4;
      int kb = (c & 15) << 4;
      int off = (row << 8) + (kb ^ ((row & 7) << 4));
      uint4 va = make_uint4(0,0,0,0);
      int gr = mbase + row;
      if (gr < M)
        va = *reinterpret_cast<const uint4*>(Ab + (size_t)gr*(lda*2) + ks*256 + kb);
      *reinterpret_cast<uint4*>(ldsA + off) = va;
    }
    __syncthreads();
    #pragma unroll
    for (int kk = 0; kk < 4; ++kk){
      int kbyte = kk*64 + (l >> 4)*16;
      short8 af[2], bf[4];
      #pragma unroll
      for (int n = 0; n < 4; ++n){
        int fc = wn + n*16 + (l & 15);
        bf[n] = *reinterpret_cast<const short8*>(
                  Btb + (size_t)(nbase + fc)*(ldb*2) + ks*256 + kbyte);
      }
      #pragma unroll
      for (int m = 0; m < 2; ++m){
        int fr = wm + m*16 + (l & 15);
        af[m] = *reinterpret_cast<const short8*>(ldsA + (fr << 8) + (kbyte ^ ((fr & 7) << 4)));
      }
      #pragma unroll
      for (int m = 0; m < 2; ++m)
        #pragma unroll
        for (int n = 0; n < 4; ++n)
          acc[m][n] = __builtin_amdgcn_mfma_f32_16x16x32_bf16(af[m], bf[n], acc[m][n], 0, 0, 0);
    }
    __syncthreads();
  }
  #pragma unroll
  for (int n = 0; n < 4; ++n){
    int gcol = nbase + wn + n*16 + (l & 15);
    float bv = bias ? bias[gcol] : 0.f;
    #pragma unroll
    for (int m = 0; m < 2; ++m){
      int grow = mbase + wm + m*16 + (l >> 4)*4;
      #pragma unroll
      for (int r = 0; r < 4; ++r){
        int gr = grow + r;
        if (gr < M){
          float val = acc[m][n][r] + bv;
          if (MODE == 1){
            o_f0[(size_t)gr*128 + gcol] = val;
            if (gcol < 64) o_h0[(size_t)gr*128 + 64 + gcol] = f2bf(val);
            else           o_h1[(size_t)gr*64 + (gcol - 64)] = f2bf(val);
          } else if (MODE == 2){
            if (gcol < 64) o_f0[(size_t)gr*64 + gcol] = val;
          } else {
            int seg = gcol >> 8, c = gcol & 255;
            if      (seg == 0) o_h1[(size_t)gr*512 + c] = f2bf(val);
            else if (seg == 1) o_h0[(size_t)gr*512 + c] = f2bf(val);
            else if (seg == 2) o_h0[(size_t)gr*512 + 256 + c] = f2bf(val);
            else               o_h1[(size_t)gr*512 + 256 + c] = f2bf(val);
          }
        }
      }
    }
  }
}

// -------------- single-pass fused attention + skip + LN (lane-partitioned)
// qs[n][0:256]=Q bf16, qs[n][256:512]=S bf16; kv[n][0:256]=K, [256:512]=V
__global__ void k_attn(const unsigned short* __restrict__ qs,
                       const unsigned short* __restrict__ kv,
                       const int* __restrict__ rowptr, const int* __restrict__ csrc,
                       const float* __restrict__ ltg, const float* __restrict__ ltb,
                       unsigned short* __restrict__ outb, int N){
  int n = blockIdx.x*4 + (threadIdx.x >> 6);
  if (n >= N) return;
  int l = threadIdx.x & 63;
  int lo = rowptr[n], hi = rowptr[n+1];
  const int l4 = l*4;
  ushort4 qu = *reinterpret_cast<const ushort4*>(qs + (size_t)n*512 + l4);
  float4 qv = make_float4(bf2f(qu.x)*0.125f, bf2f(qu.y)*0.125f,
                          bf2f(qu.z)*0.125f, bf2f(qu.w)*0.125f);
  float o0 = 0.f, o1 = 0.f, o2 = 0.f, o3 = 0.f, s = 0.f;
  int i = lo;
  for (; i + 8 <= hi; i += 8){
    ushort4 kk[8], vv[8];
    #pragma unroll
    for (int j = 0; j < 8; ++j){
      const unsigned short* row = kv + (size_t)csrc[i + j]*512 + l4;
      kk[j] = *reinterpret_cast<const ushort4*>(row);
      vv[j] = *reinterpret_cast<const ushort4*>(row + 256);
    }
    float a[8];
    #pragma unroll
    for (int j = 0; j < 8; ++j)
      a[j] = qv.x*bf2f(kk[j].x) + qv.y*bf2f(kk[j].y) + qv.z*bf2f(kk[j].z) + qv.w*bf2f(kk[j].w);
    #pragma unroll
    for (int m = 1; m < 16; m <<= 1){
      #pragma unroll
      for (int j = 0; j < 8; ++j) a[j] += __shfl_xor(a[j], m, 64);
    }
    #pragma unroll
    for (int j = 0; j < 8; ++j){
      float w = __expf(a[j]);
      s += w;
      o0 += w*bf2f(vv[j].x); o1 += w*bf2f(vv[j].y);
      o2 += w*bf2f(vv[j].z); o3 += w*bf2f(vv[j].w);
    }
  }
  for (; i < hi; ++i){
    const unsigned short* row = kv + (size_t)csrc[i]*512 + l4;
    ushort4 kk = *reinterpret_cast<const ushort4*>(row);
    ushort4 vv = *reinterpret_cast<const ushort4*>(row + 256);
    float a = qv.x*bf2f(kk.x) + qv.y*bf2f(kk.y) + qv.z*bf2f(kk.z) + qv.w*bf2f(kk.w);
    #pragma unroll
    for (int m = 1; m < 16; m <<= 1) a += __shfl_xor(a, m, 64);
    float w = __expf(a);
    s += w;
    o0 += w*bf2f(vv.x); o1 += w*bf2f(vv.y); o2 += w*bf2f(vv.z); o3 += w*bf2f(vv.w);
  }
  ushort4 su = *reinterpret_cast<const ushort4*>(qs + (size_t)n*512 + 256 + l4);
  float tx0 = bf2f(su.x), tx1 = bf2f(su.y), tx2 = bf2f(su.z), tx3 = bf2f(su.w);
  if (hi > lo){
    float r = 1.f / s;
    tx0 += o0*r; tx1 += o1*r; tx2 += o2*r; tx3 += o3*r;
  }
  float mean = wave_sum(tx0 + tx1 + tx2 + tx3) * (1.f/256.f);
  float dx = tx0 - mean, dy = tx1 - mean, dz = tx2 - mean, dw = tx3 - mean;
  float var = wave_sum(dx*dx + dy*dy + dz*dz + dw*dw) * (1.f/256.f);
  float rs = rsqrtf(var + 1e-5f);
  float4 g = *reinterpret_cast<const float4*>(ltg + l4);
  float4 b = *reinterpret_cast<const float4*>(ltb + l4);
  ushort4 o;
  o.x = f2bf(dx*rs*g.x + b.x);
  o.y = f2bf(dy*rs*g.y + b.y);
  o.z = f2bf(dz*rs*g.z + b.z);
  o.w = f2bf(dw*rs*g.w + b.w);
  *reinterpret_cast<ushort4*>(outb + (size_t)n*256 + l4) = o;
}

// ------ gated fusion (gate precomputed by MFMA) + agg update + comb-LN
// P gathered as bf16 from Pbf[N][64]
__global__ __launch_bounds__(256) void k_gate2(
    float* __restrict__ nf, float* __restrict__ agg,
    const float* __restrict__ pnP, const unsigned short* __restrict__ Pbf,
    const float* __restrict__ gate_arg,
    const int* __restrict__ rowptr, const int* __restrict__ csrc,
    const float* __restrict__ peb,
    const float* __restrict__ cg, const float* __restrict__ cbv,
    unsigned short* __restrict__ comb, unsigned short* __restrict__ gin,
    int doComb, int N){
  int n = blockIdx.x*4 + (threadIdx.x >> 6);
  if (n >= N) return;
  int l = threadIdx.x & 63;
  float g = sigm(gate_arg[(size_t)n*64 + l]);
  float nfv = nf[(size_t)n*64 + l];
  float pnv = pnP[(size_t)n*128 + l];
  float nfn = nfv * (1.f + g) + pnv * (1.f - g);
  nf[(size_t)n*64 + l] = nfn;
  gin[(size_t)n*128 + l] = f2bf(nfn);
  int lo = rowptr[n], hi = rowptr[n+1];
  float sp = 0.f;
  int i = lo;
  for (; i + 8 <= hi; i += 8){
    float pv[8];
    #pragma unroll
    for (int j = 0; j < 8; ++j)
      pv[j] = bf2f(Pbf[(size_t)csrc[i+j]*64 + l]);
    #pragma unroll
    for (int j = 0; j < 8; ++j) sp += pv[j];
  }
  for (; i < hi; ++i) sp += bf2f(Pbf[(size_t)csrc[i]*64 + l]);
  float Pn = bf2f(Pbf[(size_t)n*64 + l]);
  float aggn = agg[(size_t)n*64 + l] + sp - (float)(hi - lo) * (Pn - peb[l]);
  agg[(size_t)n*64 + l] = aggn;
  if (doComb){
    float v0 = nfn, v1 = aggn - nfn;
    float mean = wave_sum(v0 + v1) * (1.f/128.f);
    float d0 = v0 - mean, d1 = v1 - mean;
    float var = wave_sum(d0*d0 + d1*d1) * (1.f/128.f);
    float rs = rsqrtf(var + 1e-5f);
    comb[(size_t)n*128 + l]      = f2bf(d0 * rs * cg[l]      + cbv[l]);
    comb[(size_t)n*128 + 64 + l] = f2bf(d1 * rs * cg[64 + l] + cbv[64 + l]);
  }
}

// ------------------------------------------------------------- classifier
template<int K, int BN>
__global__ __launch_bounds__(256) void k_gemm(
    const float* __restrict__ in, const float* __restrict__ W, int ldw,
    const float* __restrict__ bias, float* __restrict__ out, int ldo, int nrows){
  constexpr int PAD = BN + 4;
  __shared__ float s_in[K * PAD];
  int n0 = blockIdx.x * BN;
  int tid = threadIdx.x;
  for (int idx = tid; idx < BN * K; idx += 256){
    int r = idx / K, k = idx - r * K;
    float v = (n0 + r < nrows) ? in[(size_t)(n0 + r) * K + k] : 0.f;
    s_in[k * PAD + r] = v;
  }
  __syncthreads();
  int tx = tid & 15, ty = tid >> 4;
  constexpr int NT = BN / 16;
  int col0 = blockIdx.y * 64 + tx * 4;
  float acc[NT][4] = {};
  for (int k = 0; k < K; ++k){
    const float4 wv = *reinterpret_cast<const float4*>(&W[(size_t)k * ldw + col0]);
    #pragma unroll
    for (int i = 0; i < NT; ++i){
      float cv = s_in[k * PAD + ty * NT + i];
      acc[i][0] += cv * wv.x;
      acc[i][1] += cv * wv.y;
      acc[i][2] += cv * wv.z;
      acc[i][3] += cv * wv.w;
    }
  }
  #pragma unroll
  for (int i = 0; i < NT; ++i){
    int n = n0 + ty * NT + i;
    if (n < nrows){
      float4 o = make_float4(acc[i][0], acc[i][1], acc[i][2], acc[i][3]);
      *reinterpret_cast<float4*>(&out[(size_t)n * ldo + col0]) = o;
    }
  }
}

__global__ void k_final(const float* __restrict__ AB,
                        const int* __restrict__ ei, const float* __restrict__ cb1,
                        const float* __restrict__ cw2, const float* __restrict__ cb2,
                        float* __restrict__ dout, int E){
  int e = blockIdx.x*4 + (threadIdx.x >> 6);
  if (e >= E) return;
  int l = threadIdx.x & 63;
  int i0 = ei[e], i1 = ei[E + e];
  float h = fmaxf(AB[(size_t)i0*128 + l] + AB[(size_t)i1*128 + 64 + l] + cb1[l], 0.f);
  float p = wave_sum(h * cw2[l]);
  if (l == 0) dout[e] = p + cb2[0];
}

// ===========================================================================
extern "C" void kernel_launch(void* const* d_in, const int* in_sizes, int n_in,
                              void* d_out, int out_size, void* d_ws, size_t ws_size,
                              hipStream_t stream){
  const float* x         = (const float*)d_in[0];
  const float* edge_attr = (const float*)d_in[1];
  const float* node_w    = (const float*)d_in[2];
  const float* node_b    = (const float*)d_in[3];
  const float* edge_w    = (const float*)d_in[4];
  const float* edge_b    = (const float*)d_in[5];
  const float* z_emb     = (const float*)d_in[6];
  const float* cn_w1     = (const float*)d_in[7];
  const float* cn_b1     = (const float*)d_in[8];
  const float* cn_w2     = (const float*)d_in[9];
  const float* cn_b2     = (const float*)d_in[10];
  const float* cn_cw     = (const float*)d_in[11];
  const float* cn_cb     = (const float*)d_in[12];
  const float* ce_w1     = (const float*)d_in[13];
  const float* ce_b1     = (const float*)d_in[14];
  const float* ce_w2     = (const float*)d_in[15];
  const float* ce_b2     = (const float*)d_in[16];
  const float* ce_cw     = (const float*)d_in[17];
  const float* ce_cb     = (const float*)d_in[18];
  const float* Wq        = (const float*)d_in[19];
  const float* bq        = (const float*)d_in[20];
  const float* Wk        = (const float*)d_in[21];
  const float* bk        = (const float*)d_in[22];
  const float* Wv        = (const float*)d_in[23];
  const float* bv        = (const float*)d_in[24];
  const float* Ws        = (const float*)d_in[25];
  const float* bs        = (const float*)d_in[26];
  const float* lt_g      = (const float*)d_in[27];
  const float* lt_b      = (const float*)d_in[28];
  const float* lc_g      = (const float*)d_in[29];
  const float* lc_b      = (const float*)d_in[30];
  const float* pe_w      = (const float*)d_in[31];
  const float* pe_b      = (const float*)d_in[32];
  const float* pn_w      = (const float*)d_in[33];
  const float* pn_b      = (const float*)d_in[34];
  const float* gf_w      = (const float*)d_in[35];
  const float* gf_b      = (const float*)d_in[36];
  const float* c_w1      = (const float*)d_in[37];
  const float* c_b1      = (const float*)d_in[38];
  const float* c_w2      = (const float*)d_in[39];
  const float* c_b2      = (const float*)d_in[40];
  const int*   edge_index= (const int*)d_in[41];

  const int N  = in_sizes[0] / 6;
  const int E  = in_sizes[1] / 4;
  const int E2 = 2 * E;

  // ---------------- workspace layout
  char* p = (char*)d_ws;
  auto alloc = [&](size_t bytes)->char*{
    char* r = p; p += (bytes + 255) & ~(size_t)255; return r;
  };
  char* zbase = p;
  int*            w_deg    = (int*)           alloc((size_t)N * 4);
  int*            w_cur    = (int*)           alloc((size_t)N * 4);
  unsigned*       w_pmax   = (unsigned*)      alloc(64 * 4);
  float*          w_psum   = (float*)         alloc(64 * 4);
  unsigned*       w_pmax2  = (unsigned*)      alloc(64 * 4);
  float*          w_psum2  = (float*)         alloc(64 * 4);
  size_t zbytes = (size_t)(p - zbase);
  int*            w_src    = (int*)           alloc((size_t)E2 * 4);
  int*            w_dst    = (int*)           alloc((size_t)E2 * 4);
  int*            w_rowptr = (int*)           alloc((size_t)(N + 1) * 4);
  int*            w_csrc   = (int*)           alloc((size_t)E2 * 4);
  int*            w_epos   = (int*)           alloc((size_t)E2 * 4);
  float*          w_re8    = (float*)         alloc((size_t)E2 * 8 * 4);
  float*          w_nf     = (float*)         alloc((size_t)N * 64 * 4);
  float*          w_agg    = (float*)         alloc((size_t)N * 64 * 4);
  unsigned short* w_ef0    = (unsigned short*)alloc((size_t)E2 * 64 * 2);
  float*          w_se     = (float*)         alloc((size_t)E2 * 4);
  unsigned short* w_comb   = (unsigned short*)alloc((size_t)N * 128 * 2);
  unsigned short* w_gin    = (unsigned short*)alloc((size_t)N * 128 * 2);
  float*          w_gate   = (float*)         alloc((size_t)N * 64 * 4);
  unsigned short* w_qs     = (unsigned short*)alloc((size_t)N * 512 * 2);
  unsigned short* w_kv     = (unsigned short*)alloc((size_t)N * 512 * 2);
  unsigned short* w_outb   = (unsigned short*)alloc((size_t)N * 256 * 2);
  float*          w_pnP    = (float*)         alloc((size_t)N * 128 * 4);
  unsigned short* w_Pbf    = (unsigned short*)alloc((size_t)N * 64 * 2);
  float*          w_AB     = (float*)         alloc((size_t)N * 128 * 4);
  float*          w_Wp     = (float*)         alloc((size_t)64 * 128 * 4);
  unsigned short* w_Bt     = (unsigned short*)alloc((size_t)3 * 1024 * 128 * 2);
  float*          w_bias   = (float*)         alloc((size_t)3 * 1024 * 4);
  unsigned short* w_Bt2    = (unsigned short*)alloc((size_t)3 * 128 * 256 * 2);
  float*          w_bias2  = (float*)         alloc((size_t)3 * 128 * 4);
  unsigned short* w_BtG    = (unsigned short*)alloc((size_t)3 * 128 * 128 * 2);
  float*          w_bias3  = (float*)         alloc((size_t)3 * 128 * 4);
  float*          w_ch     = (float*)         alloc(64 * 4);
  float*          w_ch2    = (float*)         alloc(64 * 4);

  hipMemsetAsync(zbase, 0, zbytes, stream);

  // ---------------- CSR + raw-edge gather + node embedding/CBAM
  k_build_edges<<<(E2 + 255)/256, 256, 0, stream>>>(edge_index, E2, E, w_src, w_dst, w_deg);
  k_scan<<<1, 1024, 0, stream>>>(w_deg, w_rowptr, N);
  k_fill<<<(E2 + 255)/256, 256, 0, stream>>>(w_src, w_dst, w_rowptr, w_cur, w_csrc, w_epos,
                                             x, edge_attr, w_re8, E2, E);
  k_embed_pool<<<256, 256, 0, stream>>>(x, node_w, node_b, z_emb, w_nf, w_pmax, w_psum, N);
  k_cbam_mlp<<<1, 64, 0, stream>>>(w_pmax, w_psum, 1.f/(float)N,
                                   cn_w1, cn_b1, cn_w2, cn_b2, w_ch);
  k_nsp<<<(N + 127)/128, 256, 0, stream>>>(w_nf, w_ch, cn_cw, cn_cb, w_gin, N);

  // ---------------- edge CBAM (streamed) -> ef0/se (CSR order) -> agg0 + comb0
  k_ecol<<<256, 256, 0, stream>>>(w_re8, edge_w, edge_b, w_pmax2, w_psum2, E2);
  k_cbam_mlp<<<1, 64, 0, stream>>>(w_pmax2, w_psum2, 1.f/(float)E2,
                                   ce_w1, ce_b1, ce_w2, ce_b2, w_ch2);
  k_erp3<<<(E2 + 127)/128, 256, 0, stream>>>(w_re8, w_epos, edge_w, edge_b, w_ch2,
                                             ce_cw, ce_cb, w_ef0, w_se, E2);
  k_aggb<<<(N + 3)/4, 256, 0, stream>>>(w_ef0, w_se, w_rowptr, w_nf,
                                        lc_g, lc_b, w_agg, w_comb, N);

  // ---------------- pack all iteration weights
  k_packT1<<<dim3(4, 6, 4), 256, 0, stream>>>(Wq, Wk, Wv, Ws, w_Bt);
  k_packT2<<<dim3(1, 12, 2), 256, 0, stream>>>(pn_w, pe_w, w_Bt2);
  k_packG<<<3*128, 128, 0, stream>>>(gf_w, w_BtG);
  k_biasp<<<3, 1024, 0, stream>>>(bq, bk, bv, bs, pn_b, gf_b, w_bias, w_bias2, w_bias3);
  k_packC<<<32, 256, 0, stream>>>(c_w1, w_Wp);

  // ---------------- message-passing iterations
  const int MB2 = (N + 63) / 64;
  for (int i = 0; i < 3; ++i){
    k_mfma<1,0><<<dim3(8, MB2), 256, 0, stream>>>(w_comb, 128,
                                                  w_Bt + (size_t)i*1024*128, 128,
                                                  w_bias + (size_t)i*1024,
                                                  nullptr, w_kv, w_qs, N);
    k_attn<<<(N + 3)/4, 256, 0, stream>>>(w_qs, w_kv, w_rowptr, w_csrc,
                                          lt_g + (size_t)i*256, lt_b + (size_t)i*256,
                                          w_outb, N);
    k_mfma<2,1><<<dim3(1, MB2), 256, 0, stream>>>(w_outb, 256,
                                                  w_Bt2 + (size_t)i*128*256, 256,
                                                  w_bias2 + (size_t)i*128,
                                                  w_pnP, w_gin, w_Pbf, N);
    k_mfma<1,2><<<dim3(1, MB2), 256, 0, stream>>>(w_gin, 128,
                                                  w_BtG + (size_t)i*128*128, 128,
                                                  w_bias3 + (size_t)i*128,
                                                  w_gate, nullptr, nullptr, N);
    int doComb = (i < 2) ? 1 : 0;
    const float* cg  = lc_g + (size_t)(i < 2 ? i+1 : 0)*128;
    const float* cbv = lc_b + (size_t)(i < 2 ? i+1 : 0)*128;
    k_gate2<<<(N + 3)/4, 256, 0, stream>>>(w_nf, w_agg, w_pnP, w_Pbf, w_gate,
                                           w_rowptr, w_csrc,
                                           pe_b + (size_t)i*64,
                                           cg, cbv, w_comb, w_gin, doComb, N);
  }

  // ---------------- classifier (fused A|B GEMM, then edge head)
  dim3 gAB((N + 63)/64, 2);
  k_gemm<64,64><<<gAB, 256, 0, stream>>>(w_nf, w_Wp, 128, nullptr, w_AB, 128, N);
  k_final<<<(E + 3)/4, 256, 0, stream>>>(w_AB, edge_index, c_b1, c_w2, c_b2,
                                         (float*)d_out, E);
}